// Round 2
// baseline (214.992 us; speedup 1.0000x reference)
//
#include <hip/hip_runtime.h>
#include <math.h>

// Problem constants
#define NPOS   65536        // 16*64*64 positions
#define NE     1024         // codebook size
#define EDIM   64
#define HW     4096         // 64*64
#define BETA   0.25

// Output layout (floats) in d_out, reference return order:
// loss(1), z_q_st(16*64*64*64), perplexity(1), min_encodings(65536*1024), indices(65536)
#define OUT_LOSS 0LL
#define OUT_ZQ   1LL
#define OUT_PERP 4194305LL
#define OUT_ENC  4194306LL
#define OUT_IDX  71303170LL

// numpy pairwise_sum for n=64 (8 accumulators, stride 8, tree combine) of squares.
// Squares are rounded separately (contract off) to match np: tmp = v**2; sum(tmp).
__device__ __forceinline__ float pairwise_sum_sq64(const float v[64]) {
#pragma clang fp contract(off)
    float r[8];
#pragma unroll
    for (int k = 0; k < 8; ++k) r[k] = v[k] * v[k];
#pragma unroll
    for (int i = 8; i < 64; i += 8) {
#pragma unroll
        for (int k = 0; k < 8; ++k) {
            float s = v[i + k] * v[i + k];
            r[k] = r[k] + s;
        }
    }
    return ((r[0] + r[1]) + (r[2] + r[3])) + ((r[4] + r[5]) + (r[6] + r[7]));
}

// K0: codebook norms + zero counts + zero loss accumulator (per launch: deterministic)
__global__ void vq_prep(const float* __restrict__ emb, float* __restrict__ enorm,
                        int* __restrict__ counts, double* __restrict__ lacc) {
    int t = blockIdx.x * 256 + threadIdx.x;   // 0..1023
    if (t < NE) {
        float v[64];
#pragma unroll
        for (int c = 0; c < 64; ++c) v[c] = emb[t * 64 + c];
        enorm[t] = pairwise_sum_sq64(v);
        counts[t] = 0;
    }
    if (t == 0) *lacc = 0.0;
}

// K1: main. grid = 1024 blocks x 256 threads.
// Block handles 64 consecutive positions (one lane each); 4 waves split the
// 1024 codes into 4 chunks of 256 (wave-uniform j -> scalar loads of codebook).
__global__ __launch_bounds__(256, 4)
void vq_main(const float* __restrict__ z, const float* __restrict__ emb,
             const float* __restrict__ enorm, int* __restrict__ counts,
             double* __restrict__ lacc, float* __restrict__ out) {
    __shared__ float dl[256];
    __shared__ int   il[256];
    __shared__ int   fidx[64];

    const int tid = threadIdx.x;
    const int l   = tid & 63;        // lane = position within block
    const int w   = tid >> 6;        // wave = codebook chunk
    const int n0  = blockIdx.x * 64; // first position of block (same image b)
    const int b   = n0 >> 12;
    const int hw0 = n0 & 4095;
    const long long zoff = (long long)b * (64LL * HW) + hw0 + l;

    // load this position's 64-dim vector (coalesced across lanes per channel)
    float zv[64];
#pragma unroll
    for (int c = 0; c < 64; ++c) zv[c] = z[zoff + (long long)c * HW];

    const float szn = pairwise_sum_sq64(zv);

    // wave-uniform chunk base (readfirstlane so the compiler proves uniformity
    // and emits s_load for the codebook rows)
    const int jbase = __builtin_amdgcn_readfirstlane(w * 256);

    float best = 3.4e38f;
    int   bi   = jbase;
#pragma unroll 2
    for (int jj = 0; jj < 256; ++jj) {
        const int j = jbase + jj;
        const float* __restrict__ erow = emb + j * 64;
        // BLAS sgemm micro-kernel order: sequential k, single accumulator, FMA
        float acc = 0.0f;
#pragma unroll
        for (int c = 0; c < 64; ++c) acc = fmaf(zv[c], erow[c], acc);
        // dist = (||z||^2 + ||e||^2) - 2*dot   (2*dot exact; fusion harmless)
        float dj = (szn + enorm[j]) - 2.0f * acc;
        if (dj < best) { best = dj; bi = j; }   // strict < : first-min wins
    }
    dl[tid] = best;
    il[tid] = bi;
    __syncthreads();

    // cross-wave argmin reduce (ascending chunk order keeps lowest index on ties)
    if (w == 0) {
        float bd = dl[l];
        int   bx = il[l];
#pragma unroll
        for (int ww = 1; ww < 4; ++ww) {
            float dw = dl[ww * 64 + l];
            int   iw = il[ww * 64 + l];
            if (dw < bd) { bd = dw; bx = iw; }
        }
        fidx[l] = bx;
        atomicAdd(&counts[bx], 1);
        out[OUT_IDX + n0 + l] = (float)bx;    // indices as f32 values
    }
    __syncthreads();

    // one-hot rows: 64 rows x 1024 floats, float2 stores (offset is 8B-aligned)
    {
        float2* __restrict__ enc = (float2*)(out + OUT_ENC);
        const int c0 = tid * 2;
        const int c1 = (tid + 256) * 2;
        for (int r = 0; r < 64; ++r) {
            const int ir = fidx[r];
            const long long rowb = (long long)(n0 + r) * 512;
            float2 v0, v1;
            v0.x = (ir == c0)     ? 1.0f : 0.0f;
            v0.y = (ir == c0 + 1) ? 1.0f : 0.0f;
            v1.x = (ir == c1)     ? 1.0f : 0.0f;
            v1.y = (ir == c1 + 1) ? 1.0f : 0.0f;
            enc[rowb + tid]       = v0;
            enc[rowb + 256 + tid] = v1;
        }
    }

    // z_q_st = z + (z_q - z)  (two rounded f32 ops, same as reference)
    // thread (w,l): position l, channels w*16..w*16+15. Also loss partials.
    const int myidx = fidx[l];
    double acc = 0.0;
#pragma unroll
    for (int k = 0; k < 16; ++k) {
        const int c = w * 16 + k;
        const float zc = z[zoff + (long long)c * HW];
        const float ec = emb[myidx * 64 + c];
        const float t  = __fsub_rn(ec, zc);      // z_q - z
        const float o  = __fadd_rn(zc, t);       // z + (z_q - z)
        out[OUT_ZQ + (long long)b * (64LL * HW) + (long long)c * HW + hw0 + l] = o;
        const float s = __fmul_rn(t, t);         // (z_q - z)^2 rounded f32
        acc += (double)s;
    }
    // wave-level f64 reduce, one atomic per wave
#pragma unroll
    for (int off = 32; off > 0; off >>= 1) acc += __shfl_down(acc, off);
    if (l == 0) atomicAdd(lacc, acc);
}

// K2: perplexity + loss finalize. 1 block x 1024 threads.
__global__ void vq_finalize(const int* __restrict__ counts,
                            const double* __restrict__ lacc,
                            float* __restrict__ out) {
    __shared__ float red[1024];
    const int t = threadIdx.x;
    const float p = (float)counts[t] * (1.0f / 65536.0f); // exact (count int, /2^16)
    const float term = p * logf(p + 1e-10f);
    red[t] = term;
    __syncthreads();
    for (int s = 512; s > 0; s >>= 1) {
        if (t < s) red[t] += red[t + s];
        __syncthreads();
    }
    if (t == 0) {
        out[OUT_PERP] = expf(-red[0]);
        out[OUT_LOSS] = (float)(BETA * (*lacc / 4194304.0));
    }
}

extern "C" void kernel_launch(void* const* d_in, const int* in_sizes, int n_in,
                              void* d_out, int out_size, void* d_ws, size_t ws_size,
                              hipStream_t stream) {
    const float* z   = (const float*)d_in[0];   // (16,64,64,64) f32
    const float* emb = (const float*)d_in[1];   // (1024,64) f32
    float* out = (float*)d_out;

    double* lacc  = (double*)d_ws;
    int*    cnts  = (int*)((char*)d_ws + 16);
    float*  enorm = (float*)((char*)d_ws + 16 + NE * sizeof(int));

    vq_prep<<<4, 256, 0, stream>>>(emb, enorm, cnts, lacc);
    vq_main<<<1024, 256, 0, stream>>>(z, emb, enorm, cnts, lacc, out);
    vq_finalize<<<1, 1024, 0, stream>>>(cnts, lacc, out);
}